// Round 16
// baseline (363.909 us; speedup 1.0000x reference)
//
#include <hip/hip_runtime.h>
#include <stdint.h>

typedef short short8 __attribute__((ext_vector_type(8)));
typedef float floatx4 __attribute__((ext_vector_type(4)));

#define M_TOK 8192
#define K_IN  4096
#define N_OUT 4096
#define NTT   (K_IN / 32)    // 128 K-tiles of 32

// ---------- bf16 helpers (manual, RNE) ----------
static __device__ __forceinline__ float bf2f(ushort u) {
    union { uint32_t u; float f; } v;
    v.u = ((uint32_t)u) << 16;
    return v.f;
}
static __device__ __forceinline__ ushort f2bf(float f) {
    union { float f; uint32_t u; } v;
    v.f = f;
    uint32_t u = v.u;
    uint32_t r = (u + 0x7FFFu + ((u >> 16) & 1u)) >> 16;
    return (ushort)r;
}

// ---------- mask element-width detection via the 2:4 invariant ----------
__global__ void detect_zero_kernel(int* __restrict__ flags) {
    if (threadIdx.x < 3) flags[1 + threadIdx.x] = 0;
}

__global__ __launch_bounds__(256) void detect_count_kernel(
    const unsigned char* __restrict__ mb, int* __restrict__ flags) {
    const ushort* mh = (const ushort*)mb;
    const unsigned int* mw = (const unsigned int*)mb;
    __shared__ int sh[3];
    if (threadIdx.x < 3) sh[threadIdx.x] = 0;
    __syncthreads();
    int s = blockIdx.x * 256 + threadIdx.x;      // 16384 samples
    int grp = s & 255;                           // rows < 1024: in-bounds at all widths
    int o   = (s * 97) & 4095;
    int c1 = 0, c2 = 0, c4 = 0;
    #pragma unroll
    for (int r = 0; r < 4; ++r) {
        size_t idx = (size_t)(4 * grp + r) * N_OUT + o;
        c1 += (mb[idx] != 0);
        c2 += (mh[idx] != 0);
        c4 += (mw[idx] != 0);
    }
    if (c1 != 2) atomicAdd(&sh[0], 1);
    if (c2 != 2) atomicAdd(&sh[1], 1);
    if (c4 != 2) atomicAdd(&sh[2], 1);
    __syncthreads();
    if (threadIdx.x == 0) {
        atomicAdd(&flags[1], sh[0]);
        atomicAdd(&flags[2], sh[1]);
        atomicAdd(&flags[3], sh[2]);
    }
}

__global__ void detect_final_kernel(int* __restrict__ flags) {
    if (threadIdx.x == 0) {
        int size = 4, best = flags[3];
        if (flags[2] < best) { size = 2; best = flags[2]; }
        if (flags[1] < best) { size = 1; }
        flags[0] = size;
    }
}

// ---------- x (f32) -> bf16 workspace ----------
__global__ __launch_bounds__(256) void convert_x_kernel(
    const float* __restrict__ xf, ushort* __restrict__ Xb) {
    const int total = M_TOK * K_IN;
    const int stride = gridDim.x * 256 * 8;
    for (int i = (blockIdx.x * 256 + threadIdx.x) * 8; i < total; i += stride) {
        floatx4 f0 = *(const floatx4*)&xf[i];
        floatx4 f1 = *(const floatx4*)&xf[i + 4];
        short8 v;
        #pragma unroll
        for (int j = 0; j < 4; ++j) v[j]     = (short)f2bf(f0[j]);
        #pragma unroll
        for (int j = 0; j < 4; ++j) v[4 + j] = (short)f2bf(f1[j]);
        *(short8*)&Xb[i] = v;
    }
}

// ---------- dequant + transpose:  Bt[o][i] = bf16( mask ? (q-8)*scale[o] : 0 ) ----------
__global__ __launch_bounds__(256) void dequant_kernel(
    const int* __restrict__ q, const void* __restrict__ maskp,
    const float* __restrict__ scales, ushort* __restrict__ Bt,
    const int* __restrict__ flagp) {
    const int msize = flagp[0];
    const int i0 = blockIdx.x * 64;      // in_f
    const int o0 = blockIdx.y * 64;      // out_f
    const int tid = threadIdx.x;
    const unsigned char* mb = (const unsigned char*)maskp;
    const ushort* mh = (const ushort*)maskp;
    const unsigned int* mi = (const unsigned int*)maskp;
    __shared__ ushort T[64][72];

    for (int p = 0; p < 16; ++p) {
        int idx = p * 256 + tid;
        int r = idx >> 6, c = idx & 63;
        size_t gi = (size_t)(i0 + r) * N_OUT + (o0 + c);
        bool m;
        if (msize == 1)      m = (mb[gi] != 0);
        else if (msize == 2) m = (mh[gi] != 0);
        else                 m = (mi[gi] != 0);
        float s = scales[o0 + c];
        float w = m ? (float)(q[gi] - 8) * s : 0.0f;
        T[r][c] = f2bf(w);
    }
    __syncthreads();
    for (int p = 0; p < 2; ++p) {
        int ol = p * 32 + (tid >> 3);
        int i8 = (tid & 7) * 8;
        short8 v;
        #pragma unroll
        for (int j = 0; j < 8; ++j) v[j] = (short)T[i8 + j][ol];
        *(short8*)&Bt[(size_t)(o0 + ol) * K_IN + i0 + i8] = v;
    }
}

// ---------- bf16 GEMM: 256x256, BK=32, 8 waves, 4-slot ring, 1-phase tiles ----------
// v16 = v15 ring + two fixes:
//  (a) v14's PROVEN-0-conflict swizzle on 64B rows: LDS[r][c] holds global
//      chunk c ^ ((r>>1)&3). Write side G=(lane&3)^((lane>>3)&3) (since
//      r = w*16 + (lane>>2) => (r>>1)&3 = (lane>>3)&3, w*8 = 0 mod 4).
//      Read side chunk = g ^ ((fr>>1)&3) (frag rows = 16a + fr => (r>>1)&3 =
//      (fr>>1)&3). Bank audit: quad = (4*(fr&1) + g^((fr>>1)&3)) mod 8 =>
//      2 lanes/quad per 16-lane group (the free case, m136). v15's fr&3
//      variant was 4-way (2.5e7 conflicts measured).
//  (b) 1 phase per tile: 12 ds_reads + stage A,B of t+3 -> bar -> lgkm(0) ->
//      32-MFMA cluster -> gate -> bar. 2 barriers/tile (halves v14's count);
//      long MFMA cluster covers the gate drain.
// Ledger (race-free): STG during t targets slot (t+3)&3 == (t-1)&3; slot
// t-1's readers lgkm-drained before end-of-(t-1) barrier, which every wave
// passed before issuing this STG. Gates: vmcnt(8) leaves {t+2,t+3} in
// flight; tail 4 -> 0 (slot-verified).
#define GL2L16(gp, lbase)                                                      \
    __builtin_amdgcn_global_load_lds(                                          \
        (const __attribute__((address_space(1))) void*)(gp),                   \
        (__attribute__((address_space(3))) void*)(lbase), 16, 0, 0)

#define MFMA16(a, b, c) __builtin_amdgcn_mfma_f32_16x16x32_bf16(a, b, c, 0, 0, 0)

__global__ __launch_bounds__(512, 2) void gemm_kernel(
    const ushort* __restrict__ X,   // [M_TOK][K_IN] bf16 bits (workspace)
    const ushort* __restrict__ Bt,  // [N_OUT][K_IN] bf16 bits (workspace)
    float* __restrict__ Y) {        // [M_TOK][N_OUT] float32
    __shared__ ushort As[4][256][32];   // 64 KiB ring
    __shared__ ushort Bs[4][256][32];   // 64 KiB ring

    const int tid  = threadIdx.x;
    const int w    = tid >> 6;          // 0..7
    const int lane = tid & 63;

    // L2/L3 locality mapping (bijective over 512 blocks)
    const int r    = blockIdx.x >> 8;          // 0..1
    const int kb   = blockIdx.x & 255;
    const int xcd  = kb & 7;
    const int j    = kb >> 3;                  // 0..31
    const int m_tile = r * 16 + (xcd & 1) * 8 + (j & 7);   // 0..31
    const int n_tile = (xcd >> 1) * 4 + (j >> 3);          // 0..15
    const int row0 = m_tile * 256;
    const int col0 = n_tile * 256;
    const int wm = w >> 2, wn = w & 3;  // per-wave C = 128x64

    floatx4 acc[8][4] = {};

    // staging map: wave w covers rows w*16 + (lane>>2) (+128 for load 1);
    // 4 lanes/row; source chunk G = (lane&3)^((lane>>3)&3) (inverse swizzle).
    const int srow   = (w << 4) + (lane >> 2);
    const int schunk = (lane & 3) ^ ((lane >> 3) & 3);
    const ushort* gA = X  + (size_t)(row0 + srow) * K_IN + schunk * 8;
    const ushort* gB = Bt + (size_t)(col0 + srow) * K_IN + schunk * 8;

    const int fr = lane & 15, g = lane >> 4;
    const int fsw = (fr >> 1) & 3;

    // stage one full 256x32 tile unit (A or B) of k-tile tt into ring slot SL
    #define STGU(gbase, arr, SL, tt)                                           \
        do {                                                                   \
            GL2L16(gbase + (size_t)(tt) * 32,                                  \
                   (char*)&arr[SL][w * 16][0] + lane * 16);                    \
            GL2L16(gbase + (size_t)128 * K_IN + (size_t)(tt) * 32,             \
                   (char*)&arr[SL][128 + w * 16][0] + lane * 16);              \
        } while (0)

    // one K-tile, single phase
    #define TILE1(SL, T)                                                       \
        do {                                                                   \
            const bool sg = (T) + 3 < NTT;                                     \
            short8 afr[8], bfr[4];                                             \
            _Pragma("unroll")                                                  \
            for (int n = 0; n < 4; ++n)                                        \
                bfr[n] = *(const short8*)&Bs[SL][wn * 64 + n * 16 + fr]        \
                             [(g ^ fsw) * 8];                                  \
            _Pragma("unroll")                                                  \
            for (int m = 0; m < 8; ++m)                                        \
                afr[m] = *(const short8*)&As[SL][wm * 128 + m * 16 + fr]       \
                             [(g ^ fsw) * 8];                                  \
            if (sg) {                                                          \
                STGU(gA, As, ((SL) + 3) & 3, (T) + 3);                         \
                STGU(gB, Bs, ((SL) + 3) & 3, (T) + 3);                         \
            }                                                                  \
            __builtin_amdgcn_s_barrier();                                      \
            asm volatile("s_waitcnt lgkmcnt(0)" ::: "memory");                 \
            __builtin_amdgcn_sched_barrier(0);                                 \
            __builtin_amdgcn_s_setprio(1);                                     \
            _Pragma("unroll")                                                  \
            for (int m = 0; m < 8; ++m)                                        \
                _Pragma("unroll")                                              \
                for (int n = 0; n < 4; ++n)                                    \
                    acc[m][n] = MFMA16(afr[m], bfr[n], acc[m][n]);             \
            __builtin_amdgcn_s_setprio(0);                                     \
            if (sg)                 { asm volatile("s_waitcnt vmcnt(8)" ::: "memory"); } \
            else if ((T) + 2 < NTT) { asm volatile("s_waitcnt vmcnt(4)" ::: "memory"); } \
            else                    { asm volatile("s_waitcnt vmcnt(0)" ::: "memory"); } \
            __builtin_amdgcn_s_barrier();                                      \
        } while (0)

    // prologue: tiles 0,1,2 staged; drain tile 0 (leave 8 = tiles 1,2)
    STGU(gA, As, 0, 0); STGU(gB, Bs, 0, 0);
    STGU(gA, As, 1, 1); STGU(gB, Bs, 1, 1);
    STGU(gA, As, 2, 2); STGU(gB, Bs, 2, 2);
    asm volatile("s_waitcnt vmcnt(8)" ::: "memory");
    __builtin_amdgcn_s_barrier();

    for (int t4 = 0; t4 < NTT / 4; ++t4) {
        const int T = t4 * 4;
        TILE1(0, T);
        TILE1(1, T + 1);
        TILE1(2, T + 2);
        TILE1(3, T + 3);
    }

    // epilogue: C/D layout col=lane&15, row=(lane>>4)*4+reg (m89-verified)
    const int fq = lane >> 4;
    #pragma unroll
    for (int m = 0; m < 8; ++m)
        #pragma unroll
        for (int n = 0; n < 4; ++n)
            #pragma unroll
            for (int i = 0; i < 4; ++i) {
                int rr = row0 + wm * 128 + m * 16 + fq * 4 + i;
                int cc = col0 + wn * 64 + n * 16 + fr;
                Y[(size_t)rr * N_OUT + cc] = acc[m][n][i];
            }
    #undef TILE1
    #undef STGU
}

// ---------- slow correct fallback (only if ws too small) ----------
__global__ __launch_bounds__(256) void fallback_kernel(
    const float* __restrict__ xf, const int* __restrict__ q,
    const void* __restrict__ maskp, const float* __restrict__ scales,
    float* __restrict__ Y, const int* __restrict__ flagp) {
    const int msize = flagp[0];
    const int o = blockIdx.x * 256 + threadIdx.x;
    const int t = blockIdx.y;
    const unsigned char* mb = (const unsigned char*)maskp;
    const ushort* mh = (const ushort*)maskp;
    const unsigned int* mi = (const unsigned int*)maskp;
    float s = scales[o];
    float acc = 0.f;
    for (int i = 0; i < K_IN; ++i) {
        float x = bf2f(f2bf(xf[(size_t)t * K_IN + i]));
        size_t gi = (size_t)i * N_OUT + o;
        bool m;
        if (msize == 1)      m = (mb[gi] != 0);
        else if (msize == 2) m = (mh[gi] != 0);
        else                 m = (mi[gi] != 0);
        if (m) acc += x * bf2f(f2bf((float)(q[gi] - 8) * s));
    }
    Y[(size_t)t * N_OUT + o] = acc;
}

extern "C" void kernel_launch(void* const* d_in, const int* in_sizes, int n_in,
                              void* d_out, int out_size, void* d_ws, size_t ws_size,
                              hipStream_t stream) {
    const float* x      = (const float*)d_in[0];
    const int*   q      = (const int*)d_in[1];
    const void*  mask   = d_in[2];
    const float* scales = (const float*)d_in[3];
    float* y = (float*)d_out;

    const size_t BT_OFF = 64;
    const size_t XB_OFF = BT_OFF + (size_t)N_OUT * K_IN * 2;   // 64 + 32MB
    const size_t need   = XB_OFF + (size_t)M_TOK * K_IN * 2;   // + 64MB

    int* flags = (int*)d_ws;
    detect_zero_kernel<<<1, 64, 0, stream>>>(flags);
    detect_count_kernel<<<64, 256, 0, stream>>>(
        (const unsigned char*)mask, flags);
    detect_final_kernel<<<1, 64, 0, stream>>>(flags);

    if (ws_size >= need) {
        ushort* Bt = (ushort*)((char*)d_ws + BT_OFF);
        ushort* Xb = (ushort*)((char*)d_ws + XB_OFF);
        convert_x_kernel<<<4096, 256, 0, stream>>>(x, Xb);
        dequant_kernel<<<dim3(K_IN / 64, N_OUT / 64), 256, 0, stream>>>(
            q, mask, scales, Bt, flags);
        gemm_kernel<<<dim3((M_TOK / 256) * (N_OUT / 256)), 512, 0, stream>>>(
            Xb, Bt, y);
    } else {
        fallback_kernel<<<dim3(N_OUT / 256, M_TOK), 256, 0, stream>>>(
            x, q, mask, scales, y, flags);
    }
}

// Round 17
// 361.610 us; speedup vs baseline: 1.0064x; 1.0064x over previous
//
#include <hip/hip_runtime.h>
#include <stdint.h>

typedef short short8 __attribute__((ext_vector_type(8)));
typedef float floatx4 __attribute__((ext_vector_type(4)));

#define M_TOK 8192
#define K_IN  4096
#define N_OUT 4096
#define NTT   (K_IN / 32)    // 128 K-tiles of 32

// ---------- bf16 helpers (manual, RNE) ----------
static __device__ __forceinline__ float bf2f(ushort u) {
    union { uint32_t u; float f; } v;
    v.u = ((uint32_t)u) << 16;
    return v.f;
}
static __device__ __forceinline__ ushort f2bf(float f) {
    union { float f; uint32_t u; } v;
    v.f = f;
    uint32_t u = v.u;
    uint32_t r = (u + 0x7FFFu + ((u >> 16) & 1u)) >> 16;
    return (ushort)r;
}

// ---------- mask element-width detection via the 2:4 invariant ----------
__global__ void detect_zero_kernel(int* __restrict__ flags) {
    if (threadIdx.x < 3) flags[1 + threadIdx.x] = 0;
}

__global__ __launch_bounds__(256) void detect_count_kernel(
    const unsigned char* __restrict__ mb, int* __restrict__ flags) {
    const ushort* mh = (const ushort*)mb;
    const unsigned int* mw = (const unsigned int*)mb;
    __shared__ int sh[3];
    if (threadIdx.x < 3) sh[threadIdx.x] = 0;
    __syncthreads();
    int s = blockIdx.x * 256 + threadIdx.x;      // 16384 samples
    int grp = s & 255;                           // rows < 1024: in-bounds at all widths
    int o   = (s * 97) & 4095;
    int c1 = 0, c2 = 0, c4 = 0;
    #pragma unroll
    for (int r = 0; r < 4; ++r) {
        size_t idx = (size_t)(4 * grp + r) * N_OUT + o;
        c1 += (mb[idx] != 0);
        c2 += (mh[idx] != 0);
        c4 += (mw[idx] != 0);
    }
    if (c1 != 2) atomicAdd(&sh[0], 1);
    if (c2 != 2) atomicAdd(&sh[1], 1);
    if (c4 != 2) atomicAdd(&sh[2], 1);
    __syncthreads();
    if (threadIdx.x == 0) {
        atomicAdd(&flags[1], sh[0]);
        atomicAdd(&flags[2], sh[1]);
        atomicAdd(&flags[3], sh[2]);
    }
}

__global__ void detect_final_kernel(int* __restrict__ flags) {
    if (threadIdx.x == 0) {
        int size = 4, best = flags[3];
        if (flags[2] < best) { size = 2; best = flags[2]; }
        if (flags[1] < best) { size = 1; }
        flags[0] = size;
    }
}

// ---------- x (f32) -> bf16 workspace ----------
__global__ __launch_bounds__(256) void convert_x_kernel(
    const float* __restrict__ xf, ushort* __restrict__ Xb) {
    const int total = M_TOK * K_IN;
    const int stride = gridDim.x * 256 * 8;
    for (int i = (blockIdx.x * 256 + threadIdx.x) * 8; i < total; i += stride) {
        floatx4 f0 = *(const floatx4*)&xf[i];
        floatx4 f1 = *(const floatx4*)&xf[i + 4];
        short8 v;
        #pragma unroll
        for (int j = 0; j < 4; ++j) v[j]     = (short)f2bf(f0[j]);
        #pragma unroll
        for (int j = 0; j < 4; ++j) v[4 + j] = (short)f2bf(f1[j]);
        *(short8*)&Xb[i] = v;
    }
}

// ---------- dequant + transpose:  Bt[o][i] = bf16( mask ? (q-8)*scale[o] : 0 ) ----------
__global__ __launch_bounds__(256) void dequant_kernel(
    const int* __restrict__ q, const void* __restrict__ maskp,
    const float* __restrict__ scales, ushort* __restrict__ Bt,
    const int* __restrict__ flagp) {
    const int msize = flagp[0];
    const int i0 = blockIdx.x * 64;      // in_f
    const int o0 = blockIdx.y * 64;      // out_f
    const int tid = threadIdx.x;
    const unsigned char* mb = (const unsigned char*)maskp;
    const ushort* mh = (const ushort*)maskp;
    const unsigned int* mi = (const unsigned int*)maskp;
    __shared__ ushort T[64][72];

    for (int p = 0; p < 16; ++p) {
        int idx = p * 256 + tid;
        int r = idx >> 6, c = idx & 63;
        size_t gi = (size_t)(i0 + r) * N_OUT + (o0 + c);
        bool m;
        if (msize == 1)      m = (mb[gi] != 0);
        else if (msize == 2) m = (mh[gi] != 0);
        else                 m = (mi[gi] != 0);
        float s = scales[o0 + c];
        float w = m ? (float)(q[gi] - 8) * s : 0.0f;
        T[r][c] = f2bf(w);
    }
    __syncthreads();
    for (int p = 0; p < 2; ++p) {
        int ol = p * 32 + (tid >> 3);
        int i8 = (tid & 7) * 8;
        short8 v;
        #pragma unroll
        for (int j = 0; j < 8; ++j) v[j] = (short)T[i8 + j][ol];
        *(short8*)&Bt[(size_t)(o0 + ol) * K_IN + i0 + i8] = v;
    }
}

// ---------- bf16 GEMM: 128x256 tile, 4 waves, BK=32, dbuf, 2 blocks/CU ----------
// v17: every prior variant ran ONE 8-wave block per CU with lockstep barriers
// => LDS-read bursts (~565cyc/tile/CU) and MFMA bursts (~620cyc) strictly
// alternate (measured 1327cyc/phase = sum + barriers). Fix per m114 (MFMA and
// memory pipes overlap fully ACROSS waves/blocks): 2 independent blocks/CU.
//   - 128x256 tile, 256 thr (4 waves), LDS dbuf 48KiB -> 2 blocks fit (96/160);
//     __launch_bounds__(256,2) keeps regs <= 256/wave (acc 128 + frags 48).
//   - per-wave work identical to v14: 12 ds_read_b128 + 32 MFMA per BK=32 tile,
//     proven-0-conflict swizzle (chunk ^= (row>>1)&3 both sides).
//   - simple 1-phase tile, vmcnt(0) gates: gate stalls now covered by the
//     sibling block, so ledger depth no longer matters.
#define GL2L16(gp, lbase)                                                      \
    __builtin_amdgcn_global_load_lds(                                          \
        (const __attribute__((address_space(1))) void*)(gp),                   \
        (__attribute__((address_space(3))) void*)(lbase), 16, 0, 0)

#define MFMA16(a, b, c) __builtin_amdgcn_mfma_f32_16x16x32_bf16(a, b, c, 0, 0, 0)

__global__ __launch_bounds__(256, 2) void gemm_kernel(
    const ushort* __restrict__ X,   // [M_TOK][K_IN] bf16 bits (workspace)
    const ushort* __restrict__ Bt,  // [N_OUT][K_IN] bf16 bits (workspace)
    float* __restrict__ Y) {        // [M_TOK][N_OUT] float32
    __shared__ ushort As[2][128][32];   // 16 KiB
    __shared__ ushort Bs[2][256][32];   // 32 KiB

    const int tid  = threadIdx.x;
    const int w    = tid >> 6;          // 0..3 (wave = N-column)
    const int lane = tid & 63;

    // locality mapping (bijective over 1024 blocks): per-XCD M/N regions
    const int xcd = blockIdx.x & 7;
    const int jj  = (blockIdx.x >> 3) & 63;
    const int rr0 = blockIdx.x >> 9;            // 0..1
    const int m_tile = rr0 * 32 + (xcd & 1) * 16 + (jj & 15);  // 0..63
    const int n_tile = (xcd >> 1) * 4 + (jj >> 4);             // 0..15
    const int row0 = m_tile * 128;
    const int col0 = n_tile * 256;

    floatx4 acc[8][4] = {};

    // staging: 4 lanes/row; row = tid>>2 (+64*l); chunk G=(tid&3)^((tid>>3)&3)
    // (row>>1)&3 == (tid>>3)&3 for all +64*l offsets.
    const int schunk = (tid & 3) ^ ((tid >> 3) & 3);
    const ushort* gA = X  + (size_t)(row0 + (tid >> 2)) * K_IN + schunk * 8;
    const ushort* gB = Bt + (size_t)(col0 + (tid >> 2)) * K_IN + schunk * 8;

    const int fr = lane & 15, g = lane >> 4;
    const int fsw = (fr >> 1) & 3;

    // stage tile tt into buffer BF: A 2 loads, B 4 loads per thread
    #define STG(BF, tt)                                                        \
        do {                                                                   \
            GL2L16(gA + (size_t)(tt) * 32,                                     \
                   (char*)&As[BF][w * 16][0] + lane * 16);                     \
            GL2L16(gA + (size_t)64 * K_IN + (size_t)(tt) * 32,                 \
                   (char*)&As[BF][64 + w * 16][0] + lane * 16);                \
            GL2L16(gB + (size_t)(tt) * 32,                                     \
                   (char*)&Bs[BF][w * 16][0] + lane * 16);                     \
            GL2L16(gB + (size_t)64 * K_IN + (size_t)(tt) * 32,                 \
                   (char*)&Bs[BF][64 + w * 16][0] + lane * 16);                \
            GL2L16(gB + (size_t)128 * K_IN + (size_t)(tt) * 32,                \
                   (char*)&Bs[BF][128 + w * 16][0] + lane * 16);               \
            GL2L16(gB + (size_t)192 * K_IN + (size_t)(tt) * 32,                \
                   (char*)&Bs[BF][192 + w * 16][0] + lane * 16);               \
        } while (0)

    // one K-tile: 12 frag reads || stage next ; bar ; lgkm ; 32 MFMA ; gate ; bar
    #define TILE(BF, T)                                                        \
        do {                                                                   \
            short8 afr[8], bfr[4];                                             \
            _Pragma("unroll")                                                  \
            for (int n = 0; n < 4; ++n)                                        \
                bfr[n] = *(const short8*)&Bs[BF][w * 64 + n * 16 + fr]         \
                             [(g ^ fsw) * 8];                                  \
            _Pragma("unroll")                                                  \
            for (int m = 0; m < 8; ++m)                                        \
                afr[m] = *(const short8*)&As[BF][m * 16 + fr][(g ^ fsw) * 8];  \
            if ((T) + 1 < NTT) STG((BF) ^ 1, (T) + 1);                         \
            __builtin_amdgcn_s_barrier();                                      \
            asm volatile("s_waitcnt lgkmcnt(0)" ::: "memory");                 \
            __builtin_amdgcn_sched_barrier(0);                                 \
            __builtin_amdgcn_s_setprio(1);                                     \
            _Pragma("unroll")                                                  \
            for (int m = 0; m < 8; ++m)                                        \
                _Pragma("unroll")                                              \
                for (int n = 0; n < 4; ++n)                                    \
                    acc[m][n] = MFMA16(afr[m], bfr[n], acc[m][n]);             \
            __builtin_amdgcn_s_setprio(0);                                     \
            asm volatile("s_waitcnt vmcnt(0)" ::: "memory");                   \
            __builtin_amdgcn_s_barrier();                                      \
        } while (0)

    // prologue: tile 0 -> buf0
    STG(0, 0);
    asm volatile("s_waitcnt vmcnt(0)" ::: "memory");
    __builtin_amdgcn_s_barrier();

    for (int t = 0; t < NTT; t += 2) {
        TILE(0, t);
        TILE(1, t + 1);
    }

    // epilogue: C/D layout col=lane&15, row=(lane>>4)*4+reg (m89-verified)
    const int fq = lane >> 4;
    #pragma unroll
    for (int m = 0; m < 8; ++m)
        #pragma unroll
        for (int n = 0; n < 4; ++n)
            #pragma unroll
            for (int i = 0; i < 4; ++i) {
                int rr = row0 + m * 16 + fq * 4 + i;
                int cc = col0 + w * 64 + n * 16 + fr;
                Y[(size_t)rr * N_OUT + cc] = acc[m][n][i];
            }
    #undef TILE
    #undef STG
}

// ---------- slow correct fallback (only if ws too small) ----------
__global__ __launch_bounds__(256) void fallback_kernel(
    const float* __restrict__ xf, const int* __restrict__ q,
    const void* __restrict__ maskp, const float* __restrict__ scales,
    float* __restrict__ Y, const int* __restrict__ flagp) {
    const int msize = flagp[0];
    const int o = blockIdx.x * 256 + threadIdx.x;
    const int t = blockIdx.y;
    const unsigned char* mb = (const unsigned char*)maskp;
    const ushort* mh = (const ushort*)maskp;
    const unsigned int* mi = (const unsigned int*)maskp;
    float s = scales[o];
    float acc = 0.f;
    for (int i = 0; i < K_IN; ++i) {
        float x = bf2f(f2bf(xf[(size_t)t * K_IN + i]));
        size_t gi = (size_t)i * N_OUT + o;
        bool m;
        if (msize == 1)      m = (mb[gi] != 0);
        else if (msize == 2) m = (mh[gi] != 0);
        else                 m = (mi[gi] != 0);
        if (m) acc += x * bf2f(f2bf((float)(q[gi] - 8) * s));
    }
    Y[(size_t)t * N_OUT + o] = acc;
}

extern "C" void kernel_launch(void* const* d_in, const int* in_sizes, int n_in,
                              void* d_out, int out_size, void* d_ws, size_t ws_size,
                              hipStream_t stream) {
    const float* x      = (const float*)d_in[0];
    const int*   q      = (const int*)d_in[1];
    const void*  mask   = d_in[2];
    const float* scales = (const float*)d_in[3];
    float* y = (float*)d_out;

    const size_t BT_OFF = 64;
    const size_t XB_OFF = BT_OFF + (size_t)N_OUT * K_IN * 2;   // 64 + 32MB
    const size_t need   = XB_OFF + (size_t)M_TOK * K_IN * 2;   // + 64MB

    int* flags = (int*)d_ws;
    detect_zero_kernel<<<1, 64, 0, stream>>>(flags);
    detect_count_kernel<<<64, 256, 0, stream>>>(
        (const unsigned char*)mask, flags);
    detect_final_kernel<<<1, 64, 0, stream>>>(flags);

    if (ws_size >= need) {
        ushort* Bt = (ushort*)((char*)d_ws + BT_OFF);
        ushort* Xb = (ushort*)((char*)d_ws + XB_OFF);
        convert_x_kernel<<<4096, 256, 0, stream>>>(x, Xb);
        dequant_kernel<<<dim3(K_IN / 64, N_OUT / 64), 256, 0, stream>>>(
            q, mask, scales, Bt, flags);
        gemm_kernel<<<dim3((M_TOK / 128) * (N_OUT / 256)), 256, 0, stream>>>(
            Xb, Bt, y);
    } else {
        fallback_kernel<<<dim3(N_OUT / 256, M_TOK), 256, 0, stream>>>(
            x, q, mask, scales, y, flags);
    }
}

// Round 18
// 360.097 us; speedup vs baseline: 1.0106x; 1.0042x over previous
//
#include <hip/hip_runtime.h>
#include <stdint.h>

typedef short short8 __attribute__((ext_vector_type(8)));
typedef float floatx4 __attribute__((ext_vector_type(4)));

#define M_TOK 8192
#define K_IN  4096
#define N_OUT 4096
#define NTT   (K_IN / 32)    // 128 K-tiles of 32

// ---------- bf16 helpers (manual, RNE) ----------
static __device__ __forceinline__ float bf2f(ushort u) {
    union { uint32_t u; float f; } v;
    v.u = ((uint32_t)u) << 16;
    return v.f;
}
static __device__ __forceinline__ ushort f2bf(float f) {
    union { float f; uint32_t u; } v;
    v.f = f;
    uint32_t u = v.u;
    uint32_t r = (u + 0x7FFFu + ((u >> 16) & 1u)) >> 16;
    return (ushort)r;
}

// ---------- mask width detect: 2:4 invariant on rows 0-3, all 4096 columns ----------
// Coalesced: width-1 reads 16KB, width-2 32KB, width-4 64KB. Single block.
// True width -> 0 violations; wrong widths fail ~2/3 of 4096 groups.
__global__ __launch_bounds__(256) void detect_kernel(
    const unsigned char* __restrict__ mb, int* __restrict__ flags) {
    const ushort* mh = (const ushort*)mb;
    const unsigned int* mw = (const unsigned int*)mb;
    __shared__ int v[3];
    if (threadIdx.x < 3) v[threadIdx.x] = 0;
    __syncthreads();
    int l0 = 0, l1 = 0, l2 = 0;
    for (int o = threadIdx.x; o < 4096; o += 256) {
        int c1 = 0, c2 = 0, c4 = 0;
        #pragma unroll
        for (int r = 0; r < 4; ++r) {
            int idx = r * N_OUT + o;
            c1 += (mb[idx] != 0);
            c2 += (mh[idx] != 0);
            c4 += (mw[idx] != 0);
        }
        l0 += (c1 != 2); l1 += (c2 != 2); l2 += (c4 != 2);
    }
    atomicAdd(&v[0], l0); atomicAdd(&v[1], l1); atomicAdd(&v[2], l2);
    __syncthreads();
    if (threadIdx.x == 0) {
        int size = 4, best = v[2];
        if (v[1] < best) { size = 2; best = v[1]; }
        if (v[0] < best) { size = 1; }
        flags[0] = size;
    }
}

// ---------- fused prep: convert x (blocks 0..4095) + dequant (blocks 4096..8191) ----------
__global__ __launch_bounds__(256) void prep_kernel(
    const float* __restrict__ xf, ushort* __restrict__ Xb,
    const int* __restrict__ q, const void* __restrict__ maskp,
    const float* __restrict__ scales, ushort* __restrict__ Bt,
    const int* __restrict__ flagp) {
    const int tid = threadIdx.x;
    if (blockIdx.x < 4096) {
        // x (f32) -> bf16, grid-stride
        const int total = M_TOK * K_IN;
        const int stride = 4096 * 256 * 8;
        for (int i = (blockIdx.x * 256 + tid) * 8; i < total; i += stride) {
            floatx4 f0 = *(const floatx4*)&xf[i];
            floatx4 f1 = *(const floatx4*)&xf[i + 4];
            short8 v;
            #pragma unroll
            for (int j = 0; j < 4; ++j) v[j]     = (short)f2bf(f0[j]);
            #pragma unroll
            for (int j = 0; j < 4; ++j) v[4 + j] = (short)f2bf(f1[j]);
            *(short8*)&Xb[i] = v;
        }
    } else {
        // dequant + transpose one 64x64 tile
        const int d  = blockIdx.x - 4096;
        const int i0 = (d & 63) * 64;        // in_f
        const int o0 = (d >> 6) * 64;        // out_f
        const int msize = flagp[0];
        const unsigned char* mb = (const unsigned char*)maskp;
        const ushort* mh = (const ushort*)maskp;
        const unsigned int* mi = (const unsigned int*)maskp;
        __shared__ ushort T[64][72];
        for (int p = 0; p < 16; ++p) {
            int idx = p * 256 + tid;
            int r = idx >> 6, c = idx & 63;
            size_t gi = (size_t)(i0 + r) * N_OUT + (o0 + c);
            bool m;
            if (msize == 1)      m = (mb[gi] != 0);
            else if (msize == 2) m = (mh[gi] != 0);
            else                 m = (mi[gi] != 0);
            float s = scales[o0 + c];
            float w = m ? (float)(q[gi] - 8) * s : 0.0f;
            T[r][c] = f2bf(w);
        }
        __syncthreads();
        for (int p = 0; p < 2; ++p) {
            int ol = p * 32 + (tid >> 3);
            int i8 = (tid & 7) * 8;
            short8 v;
            #pragma unroll
            for (int j = 0; j < 8; ++j) v[j] = (short)T[i8 + j][ol];
            *(short8*)&Bt[(size_t)(o0 + ol) * K_IN + i0 + i8] = v;
        }
    }
}

// ---------- bf16 GEMM: 128x256, 4 waves, BK=32, ring-3, 2 blocks/CU, counted gates ----------
// v18 = v17 (2 blocks/CU: sibling block fills the pipe during barriers/gates,
// m114) + ring-3 deep ledger (v14's proven lever):
//   slots s=t%3 (LDS 72KiB/block, 2 blocks = 144 <= 160);
//   during tile t stage t+2 into slot (t+2)%3 == (t-1)%3 (freed at end-of-
//   (t-1) barrier -> race-free); gate = vmcnt(6): drains stage(t+1) (6 loads/
//   thread), leaves stage(t+2) in flight. Prologue 12->6; tail 6->0.
// Swizzle (0-conflict, v14-proven): LDS[r][c] = global chunk c^((r>>1)&3);
// write G=(tid&3)^((tid>>3)&3); read chunk g^((fr>>1)&3).
#define GL2L16(gp, lbase)                                                      \
    __builtin_amdgcn_global_load_lds(                                          \
        (const __attribute__((address_space(1))) void*)(gp),                   \
        (__attribute__((address_space(3))) void*)(lbase), 16, 0, 0)

#define MFMA16(a, b, c) __builtin_amdgcn_mfma_f32_16x16x32_bf16(a, b, c, 0, 0, 0)

__global__ __launch_bounds__(256, 2) void gemm_kernel(
    const ushort* __restrict__ X,   // [M_TOK][K_IN] bf16 bits (workspace)
    const ushort* __restrict__ Bt,  // [N_OUT][K_IN] bf16 bits (workspace)
    float* __restrict__ Y) {        // [M_TOK][N_OUT] float32
    __shared__ ushort As[3][128][32];   // 24 KiB
    __shared__ ushort Bs[3][256][32];   // 48 KiB

    const int tid  = threadIdx.x;
    const int w    = tid >> 6;          // 0..3 (wave = N-column)
    const int lane = tid & 63;

    // locality mapping (bijective over 1024 blocks): per-XCD M/N regions
    const int xcd = blockIdx.x & 7;
    const int jj  = (blockIdx.x >> 3) & 63;
    const int rr0 = blockIdx.x >> 9;            // 0..1
    const int m_tile = rr0 * 32 + (xcd & 1) * 16 + (jj & 15);  // 0..63
    const int n_tile = (xcd >> 1) * 4 + (jj >> 4);             // 0..15
    const int row0 = m_tile * 128;
    const int col0 = n_tile * 256;

    floatx4 acc[8][4] = {};

    const int schunk = (tid & 3) ^ ((tid >> 3) & 3);
    const ushort* gA = X  + (size_t)(row0 + (tid >> 2)) * K_IN + schunk * 8;
    const ushort* gB = Bt + (size_t)(col0 + (tid >> 2)) * K_IN + schunk * 8;

    const int fr = lane & 15, g = lane >> 4;
    const int fsw = (fr >> 1) & 3;

    // stage tile tt into ring slot SL: A 2 loads, B 4 loads per thread
    #define STG(SL, tt)                                                        \
        do {                                                                   \
            GL2L16(gA + (size_t)(tt) * 32,                                     \
                   (char*)&As[SL][w * 16][0] + lane * 16);                     \
            GL2L16(gA + (size_t)64 * K_IN + (size_t)(tt) * 32,                 \
                   (char*)&As[SL][64 + w * 16][0] + lane * 16);                \
            GL2L16(gB + (size_t)(tt) * 32,                                     \
                   (char*)&Bs[SL][w * 16][0] + lane * 16);                     \
            GL2L16(gB + (size_t)64 * K_IN + (size_t)(tt) * 32,                 \
                   (char*)&Bs[SL][64 + w * 16][0] + lane * 16);                \
            GL2L16(gB + (size_t)128 * K_IN + (size_t)(tt) * 32,                \
                   (char*)&Bs[SL][128 + w * 16][0] + lane * 16);               \
            GL2L16(gB + (size_t)192 * K_IN + (size_t)(tt) * 32,                \
                   (char*)&Bs[SL][192 + w * 16][0] + lane * 16);               \
        } while (0)

    // one K-tile (slot SL=T%3): reads || stage T+2 ; bar ; lgkm ; 32 MFMA ;
    // gate vmcnt(6)/(0) ; bar
    #define TILE(SL, T)                                                        \
        do {                                                                   \
            const bool sg = (T) + 2 < NTT;                                     \
            short8 afr[8], bfr[4];                                             \
            _Pragma("unroll")                                                  \
            for (int n = 0; n < 4; ++n)                                        \
                bfr[n] = *(const short8*)&Bs[SL][w * 64 + n * 16 + fr]         \
                             [(g ^ fsw) * 8];                                  \
            _Pragma("unroll")                                                  \
            for (int m = 0; m < 8; ++m)                                        \
                afr[m] = *(const short8*)&As[SL][m * 16 + fr][(g ^ fsw) * 8];  \
            if (sg) STG(((SL) + 2) % 3, (T) + 2);                              \
            __builtin_amdgcn_s_barrier();                                      \
            asm volatile("s_waitcnt lgkmcnt(0)" ::: "memory");                 \
            __builtin_amdgcn_sched_barrier(0);                                 \
            __builtin_amdgcn_s_setprio(1);                                     \
            _Pragma("unroll")                                                  \
            for (int m = 0; m < 8; ++m)                                        \
                _Pragma("unroll")                                              \
                for (int n = 0; n < 4; ++n)                                    \
                    acc[m][n] = MFMA16(afr[m], bfr[n], acc[m][n]);             \
            __builtin_amdgcn_s_setprio(0);                                     \
            if (sg) { asm volatile("s_waitcnt vmcnt(6)" ::: "memory"); }       \
            else    { asm volatile("s_waitcnt vmcnt(0)" ::: "memory"); }       \
            __builtin_amdgcn_s_barrier();                                      \
        } while (0)

    // prologue: tiles 0,1 staged; drain tile 0 (leave stage(1)'s 6 loads)
    STG(0, 0);
    STG(1, 1);
    asm volatile("s_waitcnt vmcnt(6)" ::: "memory");
    __builtin_amdgcn_s_barrier();

    for (int t = 0; t < NTT; t += 3) {
        TILE(0, t);
        TILE(1, t + 1);
        TILE(2, t + 2);
    }
    // NTT = 128 not divisible by 3: handle with explicit count (128 = 42*3+2)
    // -> handled by loop above iterating t=0,3,...,126; tiles 126,127 done in
    // the t=126 iteration's first two TILEs; third TILE would be t=128 (OOB).
    // Guard: loop runs t<NTT, but TILE(2,t+2) at t=126 -> T=128 invalid.
    // (Corrected below by epilogue-guarded loop.)

    // epilogue: C/D layout col=lane&15, row=(lane>>4)*4+reg (m89-verified)
    const int fq = lane >> 4;
    #pragma unroll
    for (int m = 0; m < 8; ++m)
        #pragma unroll
        for (int n = 0; n < 4; ++n)
            #pragma unroll
            for (int i = 0; i < 4; ++i) {
                int rr = row0 + m * 16 + fq * 4 + i;
                int cc = col0 + w * 64 + n * 16 + fr;
                Y[(size_t)rr * N_OUT + cc] = acc[m][n][i];
            }
    #undef TILE
    #undef STG
}

// NOTE on the K-loop: NTT=128, loop strides 3. To keep all TILE slots
// compile-time constant AND cover 128 = 3*42 + 2 tiles, the kernel above
// must not execute TILE(2,128). We fix this by running t in [0,126) for
// full triples and then tiles 126,127 explicitly. The macro-based kernel
// is regenerated accordingly in gemm_kernel_fix (used by kernel_launch).

__global__ __launch_bounds__(256, 2) void gemm_kernel_fix(
    const ushort* __restrict__ X, const ushort* __restrict__ Bt,
    float* __restrict__ Y) {
    __shared__ ushort As[3][128][32];
    __shared__ ushort Bs[3][256][32];

    const int tid  = threadIdx.x;
    const int w    = tid >> 6;
    const int lane = tid & 63;

    const int xcd = blockIdx.x & 7;
    const int jj  = (blockIdx.x >> 3) & 63;
    const int rr0 = blockIdx.x >> 9;
    const int m_tile = rr0 * 32 + (xcd & 1) * 16 + (jj & 15);
    const int n_tile = (xcd >> 1) * 4 + (jj >> 4);
    const int row0 = m_tile * 128;
    const int col0 = n_tile * 256;

    floatx4 acc[8][4] = {};

    const int schunk = (tid & 3) ^ ((tid >> 3) & 3);
    const ushort* gA = X  + (size_t)(row0 + (tid >> 2)) * K_IN + schunk * 8;
    const ushort* gB = Bt + (size_t)(col0 + (tid >> 2)) * K_IN + schunk * 8;

    const int fr = lane & 15, g = lane >> 4;
    const int fsw = (fr >> 1) & 3;

    #define STG(SL, tt)                                                        \
        do {                                                                   \
            GL2L16(gA + (size_t)(tt) * 32,                                     \
                   (char*)&As[SL][w * 16][0] + lane * 16);                     \
            GL2L16(gA + (size_t)64 * K_IN + (size_t)(tt) * 32,                 \
                   (char*)&As[SL][64 + w * 16][0] + lane * 16);                \
            GL2L16(gB + (size_t)(tt) * 32,                                     \
                   (char*)&Bs[SL][w * 16][0] + lane * 16);                     \
            GL2L16(gB + (size_t)64 * K_IN + (size_t)(tt) * 32,                 \
                   (char*)&Bs[SL][64 + w * 16][0] + lane * 16);                \
            GL2L16(gB + (size_t)128 * K_IN + (size_t)(tt) * 32,                \
                   (char*)&Bs[SL][128 + w * 16][0] + lane * 16);               \
            GL2L16(gB + (size_t)192 * K_IN + (size_t)(tt) * 32,                \
                   (char*)&Bs[SL][192 + w * 16][0] + lane * 16);               \
        } while (0)

    #define TILE(SL, T, SG, LAST)                                              \
        do {                                                                   \
            short8 afr[8], bfr[4];                                             \
            _Pragma("unroll")                                                  \
            for (int n = 0; n < 4; ++n)                                        \
                bfr[n] = *(const short8*)&Bs[SL][w * 64 + n * 16 + fr]         \
                             [(g ^ fsw) * 8];                                  \
            _Pragma("unroll")                                                  \
            for (int m = 0; m < 8; ++m)                                        \
                afr[m] = *(const short8*)&As[SL][m * 16 + fr][(g ^ fsw) * 8];  \
            if (SG) STG(((SL) + 2) % 3, (T) + 2);                              \
            __builtin_amdgcn_s_barrier();                                      \
            asm volatile("s_waitcnt lgkmcnt(0)" ::: "memory");                 \
            __builtin_amdgcn_sched_barrier(0);                                 \
            __builtin_amdgcn_s_setprio(1);                                     \
            _Pragma("unroll")                                                  \
            for (int m = 0; m < 8; ++m)                                        \
                _Pragma("unroll")                                              \
                for (int n = 0; n < 4; ++n)                                    \
                    acc[m][n] = MFMA16(afr[m], bfr[n], acc[m][n]);             \
            __builtin_amdgcn_s_setprio(0);                                     \
            if (SG)        { asm volatile("s_waitcnt vmcnt(6)" ::: "memory"); }\
            else if (!(LAST)) { asm volatile("s_waitcnt vmcnt(0)" ::: "memory"); } \
            if (!(LAST)) __builtin_amdgcn_s_barrier();                         \
        } while (0)

    STG(0, 0);
    STG(1, 1);
    asm volatile("s_waitcnt vmcnt(6)" ::: "memory");
    __builtin_amdgcn_s_barrier();

    // 126 tiles in 42 triples (all stage: T+2 <= 127), then tiles 126,127
    for (int t = 0; t < 126; t += 3) {
        TILE(0, t,     true, false);
        TILE(1, t + 1, true, false);
        TILE(2, t + 2, true, false);
    }
    TILE(0, 126, false, false);   // drains stage(127) via vmcnt(0)
    TILE(1, 127, false, true);    // nothing in flight; no trailing barrier

    const int fq = lane >> 4;
    #pragma unroll
    for (int m = 0; m < 8; ++m)
        #pragma unroll
        for (int n = 0; n < 4; ++n)
            #pragma unroll
            for (int i = 0; i < 4; ++i) {
                int rr = row0 + m * 16 + fq * 4 + i;
                int cc = col0 + w * 64 + n * 16 + fr;
                Y[(size_t)rr * N_OUT + cc] = acc[m][n][i];
            }
    #undef TILE
    #undef STG
}

// ---------- slow correct fallback (only if ws too small) ----------
__global__ __launch_bounds__(256) void fallback_kernel(
    const float* __restrict__ xf, const int* __restrict__ q,
    const void* __restrict__ maskp, const float* __restrict__ scales,
    float* __restrict__ Y, const int* __restrict__ flagp) {
    const int msize = flagp[0];
    const int o = blockIdx.x * 256 + threadIdx.x;
    const int t = blockIdx.y;
    const unsigned char* mb = (const unsigned char*)maskp;
    const ushort* mh = (const ushort*)maskp;
    const unsigned int* mi = (const unsigned int*)maskp;
    float s = scales[o];
    float acc = 0.f;
    for (int i = 0; i < K_IN; ++i) {
        float x = bf2f(f2bf(xf[(size_t)t * K_IN + i]));
        size_t gi = (size_t)i * N_OUT + o;
        bool m;
        if (msize == 1)      m = (mb[gi] != 0);
        else if (msize == 2) m = (mh[gi] != 0);
        else                 m = (mi[gi] != 0);
        if (m) acc += x * bf2f(f2bf((float)(q[gi] - 8) * s));
    }
    Y[(size_t)t * N_OUT + o] = acc;
}

extern "C" void kernel_launch(void* const* d_in, const int* in_sizes, int n_in,
                              void* d_out, int out_size, void* d_ws, size_t ws_size,
                              hipStream_t stream) {
    const float* x      = (const float*)d_in[0];
    const int*   q      = (const int*)d_in[1];
    const void*  mask   = d_in[2];
    const float* scales = (const float*)d_in[3];
    float* y = (float*)d_out;

    const size_t BT_OFF = 64;
    const size_t XB_OFF = BT_OFF + (size_t)N_OUT * K_IN * 2;   // 64 + 32MB
    const size_t need   = XB_OFF + (size_t)M_TOK * K_IN * 2;   // + 64MB

    int* flags = (int*)d_ws;
    detect_kernel<<<1, 256, 0, stream>>>((const unsigned char*)mask, flags);

    if (ws_size >= need) {
        ushort* Bt = (ushort*)((char*)d_ws + BT_OFF);
        ushort* Xb = (ushort*)((char*)d_ws + XB_OFF);
        prep_kernel<<<8192, 256, 0, stream>>>(x, Xb, q, mask, scales, Bt, flags);
        gemm_kernel_fix<<<dim3((M_TOK / 128) * (N_OUT / 256)), 256, 0, stream>>>(
            Xb, Bt, y);
    } else {
        fallback_kernel<<<dim3(N_OUT / 256, M_TOK), 256, 0, stream>>>(
            x, q, mask, scales, y, flags);
    }
}